// Round 3
// baseline (564.211 us; speedup 1.0000x reference)
//
#include <hip/hip_runtime.h>
#include <hip/hip_bf16.h>

// UniTeacherEncoder: deformable cross-attn x2 + fusion + (degenerate) transfusion.
// Structural simplifications vs reference:
//  - mha has Lk=1 -> softmax==1 -> only the V path matters (q/k projections dead).
//  - CPB MLP is a scalar piecewise-linear function of rel -> 16K-entry lerp table.
//  - q-projection fused into offset/attn kernels (no Q buffer).
// Inputs are f32 (proven: round1==round2 bitwise with/without cvt; npz size).
// Outputs are f32 (reference output dtype).

namespace {

constexpr int kN  = 1024;
constexpr int kM  = 1024;
constexpr int kC  = 128;
constexpr int kG  = 8;
constexpr int kDH = 64;
constexpr int kND = 256;
constexpr int kB  = 2;

constexpr int   kNT    = 16384;
constexpr float kRLO   = -2.0625f;
constexpr float kRSPAN = 4.125f;

// workspace layout (floats)
constexpr size_t W_LNKV = 0;
constexpr size_t W_LNQ  = W_LNKV + 262144;
constexpr size_t W_K    = W_LNQ  + 262144;
constexpr size_t W_V    = W_K    + 262144;
constexpr size_t W_AO   = W_V    + 262144;
constexpr size_t W_XO1  = W_AO   + 1048576;
constexpr size_t W_XO2  = W_XO1  + 262144;
constexpr size_t W_FUS  = W_XO2  + 262144;
constexpr size_t W_TAB  = W_FUS  + 262144;   // 2*(kNT+1)
constexpr size_t W_VGS1 = W_TAB  + 32770;
constexpr size_t W_VGS2 = W_VGS1 + 4096;
constexpr size_t W_MOUT = W_VGS2 + 4096;
constexpr size_t W_PART = W_MOUT + 512;      // 2*2*32*128

} // namespace

__device__ __forceinline__ float wave_sum(float v) {
#pragma unroll
  for (int o = 32; o > 0; o >>= 1) v += __shfl_xor(v, o, 64);
  return v;
}
__device__ __forceinline__ float wave_max(float v) {
#pragma unroll
  for (int o = 32; o > 0; o >>= 1) v = fmaxf(v, __shfl_xor(v, o, 64));
  return v;
}

// LayerNorm over 128 channels, one block of 128 threads per token.
__global__ void k_ln(const float* __restrict__ in, float* __restrict__ out,
                     const float* __restrict__ g, const float* __restrict__ b) {
  int row = blockIdx.x, c = threadIdx.x;
  float x = in[(size_t)row * kC + c];
  __shared__ float red[2];
  float s = wave_sum(x);
  if ((c & 63) == 0) red[c >> 6] = s;
  __syncthreads();
  float m = (red[0] + red[1]) * (1.f / kC);
  __syncthreads();
  float d = x - m;
  float s2 = wave_sum(d * d);
  if ((c & 63) == 0) red[c >> 6] = s2;
  __syncthreads();
  float v = (red[0] + red[1]) * (1.f / kC);
  out[(size_t)row * kC + c] = d * rsqrtf(v + 1e-5f) * g[c] + b[c];
}

// Fused qproj + depthwise conv(k=6,s=4,pad=1) + gelu + dot(o2w) + tanh*4 -> vgs.
__global__ void k_offset(const float* __restrict__ lnq, const float* __restrict__ qw,
                         const float* __restrict__ o1w, const float* __restrict__ o1b,
                         const float* __restrict__ o2w, float* __restrict__ vgs) {
  int bg = blockIdx.x >> 8, j = blockIdx.x & 255, t = threadIdx.x;
  int b = bg >> 3, g = bg & 7;
  __shared__ float xr[6][16];
  int base = j * 4 - 1;
  if (t < 96) {
    int r = t >> 4, c = t & 15;
    int n = base + r;
    xr[r][c] = (n >= 0 && n < kN) ? lnq[((size_t)(b * kN + n)) * kC + g * 16 + c] : 0.f;
  }
  __syncthreads();
  if (t < 64) {
    const float* wq = qw + (size_t)(g * kDH + t) * 16;
    float acc = o1b[t];
#pragma unroll
    for (int k = 0; k < 6; ++k) {
      float qv = 0.f;
#pragma unroll
      for (int c = 0; c < 16; ++c) qv += xr[k][c] * wq[c];
      acc += qv * o1w[t * 6 + k];
    }
    float ge = 0.5f * acc * (1.f + erff(acc * 0.70710678118654752440f));
    float s = wave_sum(ge * o2w[t]);
    if (t == 0) {
      float off = tanhf(s) * 4.0f;
      vgs[bg * kND + j] = 2.f * ((float)j + off) / 255.f - 1.f;
    }
  }
}

// CPB MLP tabulated over rel (piecewise-linear scalar function).
__global__ void k_cpb_table(const float* __restrict__ w1, const float* __restrict__ b1,
                            const float* __restrict__ w2, const float* __restrict__ b2,
                            const float* __restrict__ w3, const float* __restrict__ b3,
                            float* __restrict__ tab) {
  int idx = blockIdx.y;
  int t = blockIdx.x * blockDim.x + threadIdx.x;
  if (t > kNT) return;
  float rel = kRLO + (kRSPAN / (float)kNT) * (float)t;
  float u = (rel >= 0.f ? 1.f : -1.f) * log1pf(fabsf(rel));
  const float* W1 = w1 + idx * 32; const float* B1 = b1 + idx * 32;
  const float* W2 = w2 + idx * 1024; const float* B2 = b2 + idx * 32;
  const float* W3 = w3 + idx * 32; const float* B3 = b3 + idx;
  float h1[32];
#pragma unroll
  for (int m = 0; m < 32; ++m) h1[m] = fmaxf(0.f, u * W1[m] + B1[m]);
  float out = B3[0];
  for (int m = 0; m < 32; ++m) {
    float a = B2[m];
#pragma unroll
    for (int k = 0; k < 32; ++k) a += h1[k] * W2[k * 32 + m];
    out += fmaxf(a, 0.f) * W3[m];
  }
  tab[(size_t)idx * (kNT + 1) + t] = out;
}

// grid_sample (zeros pad, align_corners=False) + k/v group projections.
__global__ void k_sample_kv(const float* __restrict__ lnkv, const float* __restrict__ vgs,
                            const float* __restrict__ kw, const float* __restrict__ vw,
                            float* __restrict__ kout, float* __restrict__ vout) {
  int bg = blockIdx.x >> 8, j = blockIdx.x & 255, t = threadIdx.x;
  int b = bg >> 3, g = bg & 7;
  __shared__ float sc[16];
  if (t < 16) {
    float gr = vgs[bg * kND + j];
    float x = ((gr + 1.f) * (float)kM - 1.f) * 0.5f;
    float x0f = floorf(x);
    float w1 = x - x0f;
    int x0 = (int)x0f, x1 = x0 + 1;
    const float* src = lnkv + (size_t)b * kM * kC + g * 16 + t;
    float v0 = (x0 >= 0 && x0 < kM) ? src[(size_t)x0 * kC] : 0.f;
    float v1 = (x1 >= 0 && x1 < kM) ? src[(size_t)x1 * kC] : 0.f;
    sc[t] = v0 * (1.f - w1) + v1 * w1;
  }
  __syncthreads();
  const float* kwr = kw + (size_t)(g * kDH + t) * 16;
  const float* vwr = vw + (size_t)(g * kDH + t) * 16;
  float ka = 0.f, va = 0.f;
#pragma unroll
  for (int c = 0; c < 16; ++c) { ka += sc[c] * kwr[c]; va += sc[c] * vwr[c]; }
  size_t o = ((size_t)(bg * kND + j)) * kDH + t;
  kout[o] = ka;
  vout[o] = va;
}

// Fused: on-the-fly qproj; sim = qk/8 + cpb(rel); softmax; attn f32 out; PV.
// One block (256 thr) per (bg, i).
__global__ void k_attn(const float* __restrict__ lnq, const float* __restrict__ qw,
                       const float* __restrict__ k, const float* __restrict__ v,
                       const float* __restrict__ vgs, const float* __restrict__ tab,
                       float* __restrict__ aout, float* __restrict__ attout) {
  int bg = blockIdx.x >> 10, i = blockIdx.x & 1023;
  int b = bg >> 3, g = bg & 7;
  int t = threadIdx.x;
  __shared__ float xq[16];
  __shared__ float qs[64];
  __shared__ float sattn[256];
  __shared__ float part[256];
  __shared__ float red[4];
  if (t < 16) xq[t] = lnq[((size_t)(b * kN + i)) * kC + g * 16 + t];
  __syncthreads();
  if (t < 64) {
    const float* wq = qw + (size_t)(g * kDH + t) * 16;
    float a = 0.f;
#pragma unroll
    for (int c = 0; c < 16; ++c) a += xq[c] * wq[c];
    qs[t] = a;
  }
  __syncthreads();
  const float* kr = k + ((size_t)(bg * kND + t)) * kDH;
  float sim = 0.f;
#pragma unroll 16
  for (int d = 0; d < 64; ++d) sim += qs[d] * kr[d];
  sim *= 0.125f;
  float seq_i = 2.f * (float)i / 1023.f - 1.f;
  float rel = seq_i - vgs[bg * kND + t];
  float ft = (rel - kRLO) * ((float)kNT / kRSPAN);
  ft = fminf(fmaxf(ft, 0.f), 16383.999f);
  int i0 = (int)ft;
  float fw = ft - (float)i0;
  sim += tab[i0] * (1.f - fw) + tab[i0 + 1] * fw;
  float wm = wave_max(sim);
  if ((t & 63) == 0) red[t >> 6] = wm;
  __syncthreads();
  float rowmax = fmaxf(fmaxf(red[0], red[1]), fmaxf(red[2], red[3]));
  __syncthreads();
  float e = expf(sim - rowmax);
  float wsum = wave_sum(e);
  if ((t & 63) == 0) red[t >> 6] = wsum;
  __syncthreads();
  float a = e / (red[0] + red[1] + red[2] + red[3]);
  sattn[t] = a;
  aout[((size_t)(bg * kN + i)) * kND + t] = a;
  __syncthreads();
  int d = t & 63, jc = t >> 6;
  const float* vb = v + ((size_t)(bg * kND + jc * 64)) * kDH + d;
  float acc = 0.f;
#pragma unroll 16
  for (int jj = 0; jj < 64; ++jj) acc += sattn[jc * 64 + jj] * vb[(size_t)jj * kDH];
  part[t] = acc;
  __syncthreads();
  if (t < 64)
    attout[((size_t)(bg * kN + i)) * kDH + t] =
        part[t] + part[64 + t] + part[128 + t] + part[192 + t];
}

// out-projection (128x512) + residual. One block (128 thr) per (b, n).
__global__ void k_oproj(const float* __restrict__ attout, const float* __restrict__ ow,
                        const float* __restrict__ ob, const float* __restrict__ x1,
                        float* __restrict__ xout) {
  int b = blockIdx.x >> 10, n = blockIdx.x & 1023, t = threadIdx.x;
  __shared__ float s[512];
#pragma unroll
  for (int r = 0; r < 4; ++r) {
    int c = r * 128 + t;
    int g = c >> 6, d = c & 63;
    s[c] = attout[(((size_t)(b * kG + g)) * kN + n) * kDH + d];
  }
  __syncthreads();
  float acc = ob[t];
  const float* wr = ow + (size_t)t * 512;
  for (int c = 0; c < 512; ++c) acc += s[c] * wr[c];
  size_t o = ((size_t)(b * kN + n)) * kC + t;
  xout[o] = x1[o] + acc;
}

__global__ void k_fuse(const float* __restrict__ xo1, const float* __restrict__ xo2,
                       const float* __restrict__ fw, const float* __restrict__ fb,
                       float* __restrict__ fused) {
  int b = blockIdx.x >> 10, n = blockIdx.x & 1023, t = threadIdx.x;
  __shared__ float s[256];
  size_t base = ((size_t)(b * kN + n)) * kC;
  s[t] = xo1[base + t];
  s[128 + t] = xo2[base + t];
  __syncthreads();
  float acc = fb[t];
  const float* wr = fw + (size_t)t * 256;
  for (int c = 0; c < 256; ++c) acc += s[c] * wr[c];
  fused[base + t] = acc;
}

// mha collapses to v-path: mout = (ln_tf(ln(x1_i[b,0])) @ Wv.T + bv) @ Wo.T + bo
__global__ void k_mout(const float* __restrict__ x1_0, const float* __restrict__ x1_1,
                       const float* __restrict__ ng, const float* __restrict__ nb,
                       const float* __restrict__ tfng, const float* __restrict__ tfnb,
                       const float* __restrict__ inw, const float* __restrict__ inb,
                       const float* __restrict__ ow, const float* __restrict__ ob,
                       float* __restrict__ mout) {
  int i = blockIdx.x >> 1, b = blockIdx.x & 1, t = threadIdx.x;
  __shared__ float red[2];
  __shared__ float s1[128];
  __shared__ float s2[128];
  const float* xs = (i ? x1_1 : x1_0) + (size_t)b * kN * kC;  // token 0
  float x = xs[t];
  float s = wave_sum(x);
  if ((t & 63) == 0) red[t >> 6] = s;
  __syncthreads();
  float m1 = (red[0] + red[1]) * (1.f / kC);
  __syncthreads();
  float d1 = x - m1;
  float ss = wave_sum(d1 * d1);
  if ((t & 63) == 0) red[t >> 6] = ss;
  __syncthreads();
  float v1 = (red[0] + red[1]) * (1.f / kC);
  __syncthreads();
  float t0 = d1 * rsqrtf(v1 + 1e-5f) * ng[t] + nb[t];
  s = wave_sum(t0);
  if ((t & 63) == 0) red[t >> 6] = s;
  __syncthreads();
  float m2 = (red[0] + red[1]) * (1.f / kC);
  __syncthreads();
  float d2 = t0 - m2;
  ss = wave_sum(d2 * d2);
  if ((t & 63) == 0) red[t >> 6] = ss;
  __syncthreads();
  float v2 = (red[0] + red[1]) * (1.f / kC);
  float t1 = d2 * rsqrtf(v2 + 1e-5f) * tfng[i * kC + t] + tfnb[i * kC + t];
  s1[t] = t1;
  __syncthreads();
  float vv = inb[i * 384 + 256 + t];
  const float* wr = inw + (size_t)i * 384 * kC + (size_t)(256 + t) * kC;
  for (int c = 0; c < 128; ++c) vv += s1[c] * wr[c];
  s2[t] = vv;
  __syncthreads();
  float mo = ob[i * kC + t];
  const float* wr2 = ow + (size_t)i * kC * kC + (size_t)t * kC;
  for (int c = 0; c < 128; ++c) mo += s2[c] * wr2[c];
  mout[blockIdx.x * kC + t] = mo;
}

// per-chunk token-sum of ln_tf( ln(fused) + mout ) -> deterministic partials
__global__ void k_meanz(const float* __restrict__ fused, const float* __restrict__ ng,
                        const float* __restrict__ nb, const float* __restrict__ tfng,
                        const float* __restrict__ tfnb, const float* __restrict__ mout,
                        float* __restrict__ partial) {
  int chunk = blockIdx.x;
  int b = blockIdx.y, i = blockIdx.z, c = threadIdx.x;
  __shared__ float red[2];
  float mo = mout[(i * 2 + b) * kC + c];
  float g1 = ng[c], b1 = nb[c];
  float g2 = tfng[i * kC + c], b2 = tfnb[i * kC + c];
  float acc = 0.f;
  for (int tk = 0; tk < 32; ++tk) {
    int tok = chunk * 32 + tk;
    float x = fused[((size_t)(b * kN + tok)) * kC + c];
    float s = wave_sum(x);
    if ((c & 63) == 0) red[c >> 6] = s;
    __syncthreads();
    float m1 = (red[0] + red[1]) * (1.f / kC);
    __syncthreads();
    float d1 = x - m1;
    float s2 = wave_sum(d1 * d1);
    if ((c & 63) == 0) red[c >> 6] = s2;
    __syncthreads();
    float v1 = (red[0] + red[1]) * (1.f / kC);
    __syncthreads();
    float z = d1 * rsqrtf(v1 + 1e-5f) * g1 + b1 + mo;
    float sz = wave_sum(z);
    if ((c & 63) == 0) red[c >> 6] = sz;
    __syncthreads();
    float m2 = (red[0] + red[1]) * (1.f / kC);
    __syncthreads();
    float d2 = z - m2;
    float s22 = wave_sum(d2 * d2);
    if ((c & 63) == 0) red[c >> 6] = s22;
    __syncthreads();
    float v2 = (red[0] + red[1]) * (1.f / kC);
    __syncthreads();
    acc += d2 * rsqrtf(v2 + 1e-5f) * g2 + b2;
  }
  partial[((size_t)(i * 2 + b) * 32 + chunk) * kC + c] = acc;
}

__global__ void k_final(const float* __restrict__ partial, const float* __restrict__ pw,
                        const float* __restrict__ pb, float* __restrict__ out) {
  int ib = blockIdx.x;
  int i = ib >> 1, b = ib & 1, t = threadIdx.x;
  __shared__ float s[128];
  float a = 0.f;
  for (int ch = 0; ch < 32; ++ch) a += partial[((size_t)ib * 32 + ch) * kC + t];
  s[t] = a * (1.f / (float)kN);
  __syncthreads();
  float acc = pb[i * kC + t];
  const float* wr = pw + (size_t)i * kC * kC + (size_t)t * kC;
  for (int c = 0; c < 128; ++c) acc += s[c] * wr[c];
  out[i * 256 + b * 128 + t] = tanhf(acc);
}

extern "C" void kernel_launch(void* const* d_in, const int* in_sizes, int n_in,
                              void* d_out, int out_size, void* d_ws, size_t ws_size,
                              hipStream_t stream) {
  const float* x1_0   = (const float*)d_in[0];
  const float* x1_1   = (const float*)d_in[1];
  const float* x2     = (const float*)d_in[2];
  const float* norm_g = (const float*)d_in[3];
  const float* norm_b = (const float*)d_in[4];
  const float* d_qw   = (const float*)d_in[5];
  const float* d_kw   = (const float*)d_in[6];
  const float* d_vw   = (const float*)d_in[7];
  const float* d_ow   = (const float*)d_in[8];
  const float* d_ob   = (const float*)d_in[9];
  const float* d_o1w  = (const float*)d_in[10];
  const float* d_o1b  = (const float*)d_in[11];
  const float* d_o2w  = (const float*)d_in[12];
  const float* c_w1   = (const float*)d_in[13];
  const float* c_b1   = (const float*)d_in[14];
  const float* c_w2   = (const float*)d_in[15];
  const float* c_b2   = (const float*)d_in[16];
  const float* c_w3   = (const float*)d_in[17];
  const float* c_b3   = (const float*)d_in[18];
  const float* fus_w  = (const float*)d_in[19];
  const float* fus_b  = (const float*)d_in[20];
  const float* tf_ng  = (const float*)d_in[21];
  const float* tf_nb  = (const float*)d_in[22];
  const float* tf_inw = (const float*)d_in[23];
  const float* tf_inb = (const float*)d_in[24];
  const float* tf_ow  = (const float*)d_in[25];
  const float* tf_ob  = (const float*)d_in[26];
  const float* tf_pw  = (const float*)d_in[27];
  const float* tf_pb  = (const float*)d_in[28];

  float* ws = (float*)d_ws;
  float* out = (float*)d_out;
  float* lnkv = ws + W_LNKV; float* lnq = ws + W_LNQ;
  float* kbuf = ws + W_K;   float* vbuf = ws + W_V;
  float* ao = ws + W_AO;
  float* xo1 = ws + W_XO1;  float* xo2 = ws + W_XO2;
  float* fused = ws + W_FUS; float* tab = ws + W_TAB;
  float* vgs1 = ws + W_VGS1; float* vgs2 = ws + W_VGS2;
  float* moutp = ws + W_MOUT; float* partp = ws + W_PART;

  // output layout: f1(256) | f2(256) | a1(2*8*1024*256) | a2(same) — all f32
  float* a1out = out + 512;
  float* a2out = out + 512 + (size_t)kB * kG * kN * kND;

  k_ln<<<kB * kM, 128, 0, stream>>>(x2, lnkv, norm_g, norm_b);
  k_cpb_table<<<dim3(129, 2), 128, 0, stream>>>(c_w1, c_b1, c_w2, c_b2, c_w3, c_b3, tab);

  // ---- deform stream 1 ----
  k_ln<<<kB * kN, 128, 0, stream>>>(x1_0, lnq, norm_g, norm_b);
  k_offset<<<kB * kG * kND, 128, 0, stream>>>(lnq, d_qw, d_o1w, d_o1b, d_o2w, vgs1);
  k_sample_kv<<<kB * kG * kND, 64, 0, stream>>>(lnkv, vgs1, d_kw, d_vw, kbuf, vbuf);
  k_attn<<<kB * kG * kN, 256, 0, stream>>>(lnq, d_qw, kbuf, vbuf, vgs1, tab, a1out, ao);
  k_oproj<<<kB * kN, 128, 0, stream>>>(ao, d_ow, d_ob, x1_0, xo1);

  // ---- deform stream 2 (reuses lnq/k/v/ao; serialized on one stream) ----
  k_ln<<<kB * kN, 128, 0, stream>>>(x1_1, lnq, norm_g, norm_b);
  k_offset<<<kB * kG * kND, 128, 0, stream>>>(lnq, d_qw + 8192, d_o1w + 384,
                                              d_o1b + 64, d_o2w + 64, vgs2);
  k_sample_kv<<<kB * kG * kND, 64, 0, stream>>>(lnkv, vgs2, d_kw + 8192, d_vw + 8192,
                                                kbuf, vbuf);
  k_attn<<<kB * kG * kN, 256, 0, stream>>>(lnq, d_qw + 8192, kbuf, vbuf, vgs2,
                                           tab + (kNT + 1), a2out, ao);
  k_oproj<<<kB * kN, 128, 0, stream>>>(ao, d_ow + 65536, d_ob + 128, x1_1, xo2);

  // ---- tail ----
  k_fuse<<<kB * kN, 128, 0, stream>>>(xo1, xo2, fus_w, fus_b, fused);
  k_mout<<<4, 128, 0, stream>>>(x1_0, x1_1, norm_g, norm_b, tf_ng, tf_nb,
                                tf_inw, tf_inb, tf_ow, tf_ob, moutp);
  k_meanz<<<dim3(32, kB, 2), 128, 0, stream>>>(fused, norm_g, norm_b, tf_ng, tf_nb,
                                               moutp, partp);
  k_final<<<4, 128, 0, stream>>>(partp, tf_pw, tf_pb, out);

  (void)in_sizes; (void)n_in; (void)out_size; (void)ws_size;
}

// Round 4
// 254.367 us; speedup vs baseline: 2.2181x; 2.2181x over previous
//
#include <hip/hip_runtime.h>
#include <hip/hip_bf16.h>

// UniTeacherEncoder: deformable cross-attn x2 + fusion + (degenerate) transfusion.
// Structural simplifications vs reference:
//  - mha has Lk=1 -> softmax==1 -> only the V path matters (q/k projections dead).
//  - CPB MLP is a scalar piecewise-linear function of rel -> 16K-entry lerp table.
// v4: register-blocked zero-barrier attention (16-row tiles, wave-local LDS),
//     pre-transposed weights for coalesced matvecs, wave-per-token LN/meanz.

namespace {

constexpr int kN  = 1024;
constexpr int kM  = 1024;
constexpr int kC  = 128;
constexpr int kG  = 8;
constexpr int kDH = 64;
constexpr int kND = 256;
constexpr int kB  = 2;

constexpr int   kNT    = 16384;
constexpr float kRLO   = -2.0625f;  // rel in [-2.032, 2.032] guaranteed (|off|<=4)
constexpr float kRSPAN = 4.125f;

// workspace layout (floats), all offsets multiple of 4 (16B alignment)
constexpr size_t W_LNKV = 0;                       // 2048 x 128
constexpr size_t W_LNQ  = 262144;                  // 2048 x 128 (reused per stream)
constexpr size_t W_KT   = 524288;                  // 16 bg x 64 d x 256 j (transposed K)
constexpr size_t W_V    = 786432;                  // 16 bg x 256 j x 64 d
constexpr size_t W_AO   = 1048576;                 // 16 bg x 1024 i x 64 d
constexpr size_t W_XO1  = 2097152;                 // 2048 x 128
constexpr size_t W_XO2  = 2359296;
constexpr size_t W_FUS  = 2621440;
constexpr size_t W_TAB  = 2883584;                 // 2 x 16385 (padded to 32772)
constexpr size_t W_VGS1 = 2916356;                 // 16 x 256
constexpr size_t W_VGS2 = 2920452;
constexpr size_t W_MOUT = 2924548;                 // 4 x 128
constexpr size_t W_PART = 2925060;                 // 4 x 64 x 128
constexpr size_t W_OWT1 = 2957828;                 // 512 x 128
constexpr size_t W_OWT2 = 3023364;                 // 512 x 128
constexpr size_t W_FWT  = 3088900;                 // 256 x 128

} // namespace

__device__ __forceinline__ float wave_sum(float v) {
#pragma unroll
  for (int o = 32; o > 0; o >>= 1) v += __shfl_xor(v, o, 64);
  return v;
}
__device__ __forceinline__ float wave_max(float v) {
#pragma unroll
  for (int o = 32; o > 0; o >>= 1) v = fmaxf(v, __shfl_xor(v, o, 64));
  return v;
}

// Generic small transpose: in (R x C row-major) -> out (C x R row-major).
__global__ void k_trans(const float* __restrict__ in, float* __restrict__ out,
                        int R, int C) {
  int id = blockIdx.x * 256 + threadIdx.x;
  if (id >= R * C) return;
  int o = id / C, c = id - o * C;
  out[c * R + o] = in[id];
}

// LayerNorm over 128 channels; one WAVE per token (2 ch/lane), no barriers.
__global__ void k_ln(const float* __restrict__ in, float* __restrict__ out,
                     const float* __restrict__ g, const float* __restrict__ b) {
  int w = threadIdx.x >> 6, lane = threadIdx.x & 63;
  int row = blockIdx.x * 4 + w;
  const float* xr = in + (size_t)row * kC;
  float xa = xr[lane], xb = xr[lane + 64];
  float m = wave_sum(xa + xb) * (1.f / kC);
  float da = xa - m, db = xb - m;
  float v = wave_sum(da * da + db * db) * (1.f / kC);
  float r = rsqrtf(v + 1e-5f);
  float* orow = out + (size_t)row * kC;
  orow[lane]      = da * r * g[lane] + b[lane];
  orow[lane + 64] = db * r * g[lane + 64] + b[lane + 64];
}

// Fused qproj + depthwise conv(k=6,s=4,pad=1) + gelu + dot(o2w) + tanh*4 -> vgs.
// One WAVE per (bg, j); block = 4 j's; wave-local LDS, no barriers.
__global__ void k_offset(const float* __restrict__ lnq, const float* __restrict__ qw,
                         const float* __restrict__ o1w, const float* __restrict__ o1b,
                         const float* __restrict__ o2w, float* __restrict__ vgs) {
  int w = threadIdx.x >> 6, lane = threadIdx.x & 63;
  int bg = blockIdx.x >> 6, j = ((blockIdx.x & 63) << 2) + w;
  int b = bg >> 3, g = bg & 7;
  __shared__ float xr[4][96];
  int base = j * 4 - 1;
#pragma unroll
  for (int rep = 0; rep < 2; ++rep) {
    int idx = lane + rep * 64;
    if (idx < 96) {
      int r = idx >> 4, c = idx & 15, n = base + r;
      xr[w][idx] = (n >= 0 && n < kN)
                       ? lnq[((size_t)(b * kN + n)) * kC + g * 16 + c] : 0.f;
    }
  }
  // wave-local write->read: compiler orders via lgkmcnt
  const float* wq = qw + (size_t)(g * kDH + lane) * 16;
  float acc = o1b[lane];
#pragma unroll
  for (int k2 = 0; k2 < 6; ++k2) {
    float qv = 0.f;
#pragma unroll
    for (int c = 0; c < 16; ++c) qv += xr[w][k2 * 16 + c] * wq[c];
    acc += qv * o1w[lane * 6 + k2];
  }
  float ge = 0.5f * acc * (1.f + erff(acc * 0.70710678118654752440f));
  float s = wave_sum(ge * o2w[lane]);
  if (lane == 0)
    vgs[bg * kND + j] = 2.f * ((float)j + tanhf(s) * 4.0f) / 255.f - 1.f;
}

// CPB MLP tabulated over rel (piecewise-linear scalar function of one var).
__global__ void k_cpb_table(const float* __restrict__ w1, const float* __restrict__ b1,
                            const float* __restrict__ w2, const float* __restrict__ b2,
                            const float* __restrict__ w3, const float* __restrict__ b3,
                            float* __restrict__ tab) {
  int idx = blockIdx.y;
  int t = blockIdx.x * blockDim.x + threadIdx.x;
  if (t > kNT) return;
  float rel = kRLO + (kRSPAN / (float)kNT) * (float)t;
  float u = (rel >= 0.f ? 1.f : -1.f) * log1pf(fabsf(rel));
  const float* W1 = w1 + idx * 32; const float* B1 = b1 + idx * 32;
  const float* W2 = w2 + idx * 1024; const float* B2 = b2 + idx * 32;
  const float* W3 = w3 + idx * 32; const float* B3 = b3 + idx;
  float h1[32];
#pragma unroll
  for (int m = 0; m < 32; ++m) h1[m] = fmaxf(0.f, u * W1[m] + B1[m]);
  float out = B3[0];
  for (int m = 0; m < 32; ++m) {
    float a = B2[m];
#pragma unroll
    for (int k = 0; k < 32; ++k) a += h1[k] * W2[k * 32 + m];
    out += fmaxf(a, 0.f) * W3[m];
  }
  tab[(size_t)idx * (kNT + 1) + t] = out;
}

// grid_sample (zeros pad, align_corners=False) + k/v projections.
// One WAVE per (bg, j); writes Kt (d-major, scattered) and V (j-major, coalesced).
__global__ void k_sample_kv(const float* __restrict__ lnkv, const float* __restrict__ vgs,
                            const float* __restrict__ kw, const float* __restrict__ vw,
                            float* __restrict__ ktout, float* __restrict__ vout) {
  int w = threadIdx.x >> 6, lane = threadIdx.x & 63;
  int bg = blockIdx.x >> 6, j = ((blockIdx.x & 63) << 2) + w;
  int b = bg >> 3, g = bg & 7;
  __shared__ float sc[4][16];
  if (lane < 16) {
    float gr = vgs[bg * kND + j];
    float x = ((gr + 1.f) * (float)kM - 1.f) * 0.5f;
    float x0f = floorf(x);
    float w1 = x - x0f;
    int x0 = (int)x0f, x1 = x0 + 1;
    const float* src = lnkv + (size_t)b * kM * kC + g * 16 + lane;
    float v0 = (x0 >= 0 && x0 < kM) ? src[(size_t)x0 * kC] : 0.f;
    float v1 = (x1 >= 0 && x1 < kM) ? src[(size_t)x1 * kC] : 0.f;
    sc[w][lane] = v0 * (1.f - w1) + v1 * w1;
  }
  const float* kwr = kw + (size_t)(g * kDH + lane) * 16;
  const float* vwr = vw + (size_t)(g * kDH + lane) * 16;
  float ka = 0.f, va = 0.f;
#pragma unroll
  for (int c = 0; c < 16; ++c) { ka += sc[w][c] * kwr[c]; va += sc[w][c] * vwr[c]; }
  ktout[(size_t)bg * (kDH * kND) + lane * kND + j] = ka;     // Kt[bg][d][j]
  vout[((size_t)(bg * kND + j)) * kDH + lane] = va;          // V[bg][j][d]
}

// Register-blocked fused attention. Block = (bg, 16-row tile), 256 thr, ZERO barriers.
// Wave w owns rows 4w..4w+3 end-to-end (all LDS deps wave-local).
__global__ void __launch_bounds__(256, 4)
k_attn(const float* __restrict__ lnq, const float* __restrict__ qw,
       const float* __restrict__ kt, const float* __restrict__ v,
       const float* __restrict__ vgs, const float* __restrict__ tab,
       float* __restrict__ aout, float* __restrict__ attout) {
  int bg = blockIdx.x >> 6, tile = blockIdx.x & 63;
  int b = bg >> 3, g = bg & 7;
  int i0 = tile * 16;
  int t = threadIdx.x;
  int w = t >> 6, lane = t & 63;
  int rw0 = w * 4;  // wave's first row (tile-local)

  __shared__ float xq[16 * 16];
  __shared__ float qs[16 * 64];
  __shared__ float sattn[16 * 260];  // pad 260: PV b128 reads of 4 rows hit distinct banks

  // ---- stage x (wave-local: lane l stages xq[4w + (l>>4)][l&15]) ----
  {
    int row = rw0 + (lane >> 4), c = lane & 15;
    xq[row * 16 + c] = lnq[((size_t)(b * kN + i0 + row)) * kC + g * 16 + c];
  }
  // ---- qproj: lane o computes q[4w+r][o] (reads same wave's xq rows) ----
  {
    const float* wqp = qw + (size_t)(g * kDH + lane) * 16;
    float4 w0 = *(const float4*)(wqp + 0);
    float4 w1 = *(const float4*)(wqp + 4);
    float4 w2 = *(const float4*)(wqp + 8);
    float4 w3 = *(const float4*)(wqp + 12);
#pragma unroll
    for (int r = 0; r < 4; ++r) {
      int row = rw0 + r;
      const float4* xp = (const float4*)&xq[row * 16];
      float4 x0 = xp[0], x1 = xp[1], x2 = xp[2], x3 = xp[3];
      float q = x0.x * w0.x + x0.y * w0.y + x0.z * w0.z + x0.w * w0.w
              + x1.x * w1.x + x1.y * w1.y + x1.z * w1.z + x1.w * w1.w
              + x2.x * w2.x + x2.y * w2.y + x2.z * w2.z + x2.w * w2.w
              + x3.x * w3.x + x3.y * w3.y + x3.z * w3.z + x3.w * w3.w;
      qs[row * 64 + lane] = q;
    }
  }
  // ---- QK: thread = 4 rows (wave's) x 4 cols; Kt coalesced from L2 ----
  int c0 = lane * 4;
  float4 sim0 = {0, 0, 0, 0}, sim1 = {0, 0, 0, 0}, sim2 = {0, 0, 0, 0}, sim3 = {0, 0, 0, 0};
  const float* ktb = kt + (size_t)bg * (kDH * kND);
#pragma unroll 4
  for (int d0 = 0; d0 < 64; d0 += 4) {
    float4 q0 = *(const float4*)&qs[(rw0 + 0) * 64 + d0];
    float4 q1 = *(const float4*)&qs[(rw0 + 1) * 64 + d0];
    float4 q2 = *(const float4*)&qs[(rw0 + 2) * 64 + d0];
    float4 q3 = *(const float4*)&qs[(rw0 + 3) * 64 + d0];
#pragma unroll
    for (int dd = 0; dd < 4; ++dd) {
      float4 kd = *(const float4*)&ktb[(d0 + dd) * kND + c0];
      float a0 = dd == 0 ? q0.x : dd == 1 ? q0.y : dd == 2 ? q0.z : q0.w;
      float a1 = dd == 0 ? q1.x : dd == 1 ? q1.y : dd == 2 ? q1.z : q1.w;
      float a2 = dd == 0 ? q2.x : dd == 1 ? q2.y : dd == 2 ? q2.z : q2.w;
      float a3 = dd == 0 ? q3.x : dd == 1 ? q3.y : dd == 2 ? q3.z : q3.w;
      sim0.x += a0 * kd.x; sim0.y += a0 * kd.y; sim0.z += a0 * kd.z; sim0.w += a0 * kd.w;
      sim1.x += a1 * kd.x; sim1.y += a1 * kd.y; sim1.z += a1 * kd.z; sim1.w += a1 * kd.w;
      sim2.x += a2 * kd.x; sim2.y += a2 * kd.y; sim2.z += a2 * kd.z; sim2.w += a2 * kd.w;
      sim3.x += a3 * kd.x; sim3.y += a3 * kd.y; sim3.z += a3 * kd.z; sim3.w += a3 * kd.w;
    }
  }
  // ---- bias + softmax (in-register, shfl reductions) ----
  float4 vg = *(const float4*)&vgs[bg * kND + c0];
  float4 sims[4] = {sim0, sim1, sim2, sim3};
#pragma unroll
  for (int r = 0; r < 4; ++r) {
    int i = i0 + rw0 + r;
    float seq = 2.f * (float)i / 1023.f - 1.f;
    float* sp = (float*)&sims[r];
#pragma unroll
    for (int c = 0; c < 4; ++c) {
      float rel = seq - ((const float*)&vg)[c];
      float ft = (rel - kRLO) * ((float)kNT / kRSPAN);
      ft = fminf(fmaxf(ft, 0.f), 16383.999f);
      int ix = (int)ft;
      float fw = ft - (float)ix;
      sp[c] = sp[c] * 0.125f + tab[ix] * (1.f - fw) + tab[ix + 1] * fw;
    }
    float m = fmaxf(fmaxf(sp[0], sp[1]), fmaxf(sp[2], sp[3]));
    m = wave_max(m);
    float e0 = expf(sp[0] - m), e1 = expf(sp[1] - m),
          e2 = expf(sp[2] - m), e3 = expf(sp[3] - m);
    float s = wave_sum(e0 + e1 + e2 + e3);
    float inv = 1.f / s;
    float4 a4 = {e0 * inv, e1 * inv, e2 * inv, e3 * inv};
    *(float4*)&aout[((size_t)(bg * kN + i)) * kND + c0] = a4;
    *(float4*)&sattn[(rw0 + r) * 260 + c0] = a4;
  }
  // ---- PV: lane = (dg = lane&15 -> 4 d's, rsel = lane>>4 -> row 4w+rsel) ----
  {
    int dg = lane & 15, rsel = lane >> 4;
    int row = rw0 + rsel;
    int d0 = dg * 4;
    const float* vb = v + (size_t)bg * (kND * kDH);
    float4 acc = {0, 0, 0, 0};
#pragma unroll 4
    for (int j0 = 0; j0 < 256; j0 += 4) {
      float4 pa = *(const float4*)&sattn[row * 260 + j0];
      float4 v0 = *(const float4*)&vb[(j0 + 0) * kDH + d0];
      float4 v1 = *(const float4*)&vb[(j0 + 1) * kDH + d0];
      float4 v2 = *(const float4*)&vb[(j0 + 2) * kDH + d0];
      float4 v3 = *(const float4*)&vb[(j0 + 3) * kDH + d0];
      acc.x += pa.x * v0.x + pa.y * v1.x + pa.z * v2.x + pa.w * v3.x;
      acc.y += pa.x * v0.y + pa.y * v1.y + pa.z * v2.y + pa.w * v3.y;
      acc.z += pa.x * v0.z + pa.y * v1.z + pa.z * v2.z + pa.w * v3.z;
      acc.w += pa.x * v0.w + pa.y * v1.w + pa.z * v2.w + pa.w * v3.w;
    }
    *(float4*)&attout[((size_t)(bg * kN + i0 + row)) * kDH + d0] = acc;
  }
}

// out-projection (128 out x 512 in, transposed weights) + residual.
// Block = 8 tokens, 256 thr: (o = t&127, th = t>>7) each does 4 tokens.
__global__ void k_oproj(const float* __restrict__ attout, const float* __restrict__ owT,
                        const float* __restrict__ ob, const float* __restrict__ x1,
                        float* __restrict__ xout) {
  int tok0 = blockIdx.x * 8;
  int t = threadIdx.x;
  int o = t & 127, th = t >> 7;
  __shared__ float s[8 * 512];
#pragma unroll
  for (int k = 0; k < 16; ++k) {
    int fi = t + k * 256;
    int tok = fi >> 9, c = fi & 511;
    int gt = tok0 + tok;
    s[fi] = attout[(((size_t)((gt >> 10) * kG + (c >> 6))) * kN + (gt & 1023)) * kDH + (c & 63)];
  }
  __syncthreads();
  float acc0 = 0.f, acc1 = 0.f, acc2 = 0.f, acc3 = 0.f;
  for (int c = 0; c < 512; c += 4) {
    float4 w0 = *(const float4*)0;  // placeholder avoided below
    (void)w0;
    float wa = owT[(c + 0) * kC + o];
    float wb = owT[(c + 1) * kC + o];
    float wc = owT[(c + 2) * kC + o];
    float wd = owT[(c + 3) * kC + o];
    const float4 sa = *(const float4*)&s[(th + 0) * 512 + c];
    const float4 sb = *(const float4*)&s[(th + 2) * 512 + c];
    const float4 sc4 = *(const float4*)&s[(th + 4) * 512 + c];
    const float4 sd = *(const float4*)&s[(th + 6) * 512 + c];
    acc0 += sa.x * wa + sa.y * wb + sa.z * wc + sa.w * wd;
    acc1 += sb.x * wa + sb.y * wb + sb.z * wc + sb.w * wd;
    acc2 += sc4.x * wa + sc4.y * wb + sc4.z * wc + sc4.w * wd;
    acc3 += sd.x * wa + sd.y * wb + sd.z * wc + sd.w * wd;
  }
  float bias = ob[o];
  float accs[4] = {acc0, acc1, acc2, acc3};
#pragma unroll
  for (int k = 0; k < 4; ++k) {
    int gt = tok0 + th + k * 2;
    size_t oo = (size_t)gt * kC + o;
    xout[oo] = x1[oo] + accs[k] + bias;
  }
}

// fusion: concat(xo1,xo2) @ fus_w.T + fus_b (transposed weights).
__global__ void k_fuse(const float* __restrict__ xo1, const float* __restrict__ xo2,
                       const float* __restrict__ fwT, const float* __restrict__ fb,
                       float* __restrict__ fused) {
  int tok0 = blockIdx.x * 8;
  int t = threadIdx.x;
  int o = t & 127, th = t >> 7;
  __shared__ float s[8 * 256];
#pragma unroll
  for (int k = 0; k < 8; ++k) {
    int fi = t + k * 256;
    int tok = fi >> 8, c = fi & 255;
    const float* src = (c < 128) ? xo1 : xo2;
    s[fi] = src[(size_t)(tok0 + tok) * kC + (c & 127)];
  }
  __syncthreads();
  float acc0 = 0.f, acc1 = 0.f, acc2 = 0.f, acc3 = 0.f;
  for (int c = 0; c < 256; c += 4) {
    float wa = fwT[(c + 0) * kC + o];
    float wb = fwT[(c + 1) * kC + o];
    float wc = fwT[(c + 2) * kC + o];
    float wd = fwT[(c + 3) * kC + o];
    const float4 sa = *(const float4*)&s[(th + 0) * 256 + c];
    const float4 sb = *(const float4*)&s[(th + 2) * 256 + c];
    const float4 sc4 = *(const float4*)&s[(th + 4) * 256 + c];
    const float4 sd = *(const float4*)&s[(th + 6) * 256 + c];
    acc0 += sa.x * wa + sa.y * wb + sa.z * wc + sa.w * wd;
    acc1 += sb.x * wa + sb.y * wb + sb.z * wc + sb.w * wd;
    acc2 += sc4.x * wa + sc4.y * wb + sc4.z * wc + sc4.w * wd;
    acc3 += sd.x * wa + sd.y * wb + sd.z * wc + sd.w * wd;
  }
  float bias = fb[o];
  float accs[4] = {acc0, acc1, acc2, acc3};
#pragma unroll
  for (int k = 0; k < 4; ++k)
    fused[(size_t)(tok0 + th + k * 2) * kC + o] = accs[k] + bias;
}

// mha collapses to v-path: mout = (ln_tf(ln(x1_i[b,0])) @ Wv.T + bv) @ Wo.T + bo
__global__ void k_mout(const float* __restrict__ x1_0, const float* __restrict__ x1_1,
                       const float* __restrict__ ng, const float* __restrict__ nb,
                       const float* __restrict__ tfng, const float* __restrict__ tfnb,
                       const float* __restrict__ inw, const float* __restrict__ inb,
                       const float* __restrict__ ow, const float* __restrict__ ob,
                       float* __restrict__ mout) {
  int i = blockIdx.x >> 1, b = blockIdx.x & 1, t = threadIdx.x;
  __shared__ float red[2];
  __shared__ float s1[128];
  __shared__ float s2[128];
  const float* xs = (i ? x1_1 : x1_0) + (size_t)b * kN * kC;  // token 0
  float x = xs[t];
  float s = wave_sum(x);
  if ((t & 63) == 0) red[t >> 6] = s;
  __syncthreads();
  float m1 = (red[0] + red[1]) * (1.f / kC);
  __syncthreads();
  float d1 = x - m1;
  float ss = wave_sum(d1 * d1);
  if ((t & 63) == 0) red[t >> 6] = ss;
  __syncthreads();
  float v1 = (red[0] + red[1]) * (1.f / kC);
  __syncthreads();
  float t0 = d1 * rsqrtf(v1 + 1e-5f) * ng[t] + nb[t];
  s = wave_sum(t0);
  if ((t & 63) == 0) red[t >> 6] = s;
  __syncthreads();
  float m2 = (red[0] + red[1]) * (1.f / kC);
  __syncthreads();
  float d2 = t0 - m2;
  ss = wave_sum(d2 * d2);
  if ((t & 63) == 0) red[t >> 6] = ss;
  __syncthreads();
  float v2 = (red[0] + red[1]) * (1.f / kC);
  float t1 = d2 * rsqrtf(v2 + 1e-5f) * tfng[i * kC + t] + tfnb[i * kC + t];
  s1[t] = t1;
  __syncthreads();
  {
    float a0 = 0.f, a1 = 0.f, a2 = 0.f, a3 = 0.f;
    const float* wr = inw + (size_t)i * 384 * kC + (size_t)(256 + t) * kC;
    for (int c = 0; c < 128; c += 4) {
      a0 += s1[c] * wr[c]; a1 += s1[c + 1] * wr[c + 1];
      a2 += s1[c + 2] * wr[c + 2]; a3 += s1[c + 3] * wr[c + 3];
    }
    s2[t] = inb[i * 384 + 256 + t] + a0 + a1 + a2 + a3;
  }
  __syncthreads();
  {
    float a0 = 0.f, a1 = 0.f, a2 = 0.f, a3 = 0.f;
    const float* wr2 = ow + (size_t)i * kC * kC + (size_t)t * kC;
    for (int c = 0; c < 128; c += 4) {
      a0 += s2[c] * wr2[c]; a1 += s2[c + 1] * wr2[c + 1];
      a2 += s2[c + 2] * wr2[c + 2]; a3 += s2[c + 3] * wr2[c + 3];
    }
    mout[blockIdx.x * kC + t] = ob[i * kC + t] + a0 + a1 + a2 + a3;
  }
}

// Double-LN + mout add, one WAVE per token (2 ch/lane), no barriers.
// Block covers 16 tokens (4 waves x 4 iters); partial sums per chunk.
__global__ void k_meanz(const float* __restrict__ fused, const float* __restrict__ ng,
                        const float* __restrict__ nb, const float* __restrict__ tfng,
                        const float* __restrict__ tfnb, const float* __restrict__ mout,
                        float* __restrict__ partial) {
  int chunk = blockIdx.x, b = blockIdx.y, i = blockIdx.z;
  int w = threadIdx.x >> 6, lane = threadIdx.x & 63;
  int c = lane, c2 = lane + 64;
  float moa = mout[(i * 2 + b) * kC + c], mob = mout[(i * 2 + b) * kC + c2];
  float g1a = ng[c], b1a = nb[c], g1b = ng[c2], b1b = nb[c2];
  float g2a = tfng[i * kC + c], b2a = tfnb[i * kC + c];
  float g2b = tfng[i * kC + c2], b2b = tfnb[i * kC + c2];
  float acca = 0.f, accb = 0.f;
#pragma unroll
  for (int it = 0; it < 4; ++it) {
    int tok = chunk * 16 + it * 4 + w;
    const float* xr = fused + ((size_t)(b * kN + tok)) * kC;
    float xa = xr[c], xb = xr[c2];
    float m1 = wave_sum(xa + xb) * (1.f / kC);
    float da = xa - m1, db = xb - m1;
    float v1 = wave_sum(da * da + db * db) * (1.f / kC);
    float r1 = rsqrtf(v1 + 1e-5f);
    float za = da * r1 * g1a + b1a + moa;
    float zb = db * r1 * g1b + b1b + mob;
    float m2 = wave_sum(za + zb) * (1.f / kC);
    float ea = za - m2, eb = zb - m2;
    float v2 = wave_sum(ea * ea + eb * eb) * (1.f / kC);
    float r2 = rsqrtf(v2 + 1e-5f);
    acca += ea * r2 * g2a + b2a;
    accb += eb * r2 * g2b + b2b;
  }
  // waves write disjoint... all 4 waves accumulated different tokens into regs;
  // reduce across waves via separate chunk slots: chunk index includes wave? No —
  // each wave handled tokens of the same chunk; sum across waves in LDS.
  __shared__ float red[4][128];
  red[w][c] = acca; red[w][c2] = accb;
  __syncthreads();
  if (w == 0) {
    float pa = red[0][c] + red[1][c] + red[2][c] + red[3][c];
    float pb = red[0][c2] + red[1][c2] + red[2][c2] + red[3][c2];
    float* pr = partial + ((size_t)(i * 2 + b) * 64 + chunk) * kC;
    pr[c] = pa; pr[c2] = pb;
  }
}

__global__ void k_final(const float* __restrict__ partial, const float* __restrict__ pw,
                        const float* __restrict__ pb, float* __restrict__ out) {
  int ib = blockIdx.x;
  int i = ib >> 1, b = ib & 1, t = threadIdx.x;
  int c = t & 127, half = t >> 7;
  float a = 0.f;
  for (int ch = half * 32; ch < half * 32 + 32; ++ch)
    a += partial[((size_t)ib * 64 + ch) * kC + c];
  __shared__ float s[256];
  s[half * 128 + c] = a;
  __syncthreads();
  if (t < 128) {
    float val = (s[t] + s[128 + t]) * (1.f / (float)kN);
    s[t] = val;
  }
  __syncthreads();
  if (t < 128) {
    float a0 = 0.f, a1 = 0.f, a2 = 0.f, a3 = 0.f;
    const float* wr = pw + (size_t)i * kC * kC + (size_t)t * kC;
    for (int cc = 0; cc < 128; cc += 4) {
      a0 += s[cc] * wr[cc]; a1 += s[cc + 1] * wr[cc + 1];
      a2 += s[cc + 2] * wr[cc + 2]; a3 += s[cc + 3] * wr[cc + 3];
    }
    out[i * 256 + b * 128 + t] = tanhf(pb[i * kC + t] + a0 + a1 + a2 + a3);
  }
}

extern "C" void kernel_launch(void* const* d_in, const int* in_sizes, int n_in,
                              void* d_out, int out_size, void* d_ws, size_t ws_size,
                              hipStream_t stream) {
  const float* x1_0   = (const float*)d_in[0];
  const float* x1_1   = (const float*)d_in[1];
  const float* x2     = (const float*)d_in[2];
  const float* norm_g = (const float*)d_in[3];
  const float* norm_b = (const float*)d_in[4];
  const float* d_qw   = (const float*)d_in[5];
  const float* d_kw   = (const float*)d_in[6];
  const float* d_vw   = (const float*)d_in[7];
  const float* d_ow   = (const float*)d_in[8];
  const float* d_ob   = (const float*)d_in[9];
  const float* d_o1w  = (const float*)d_in[10];
  const float* d_o1b  = (const float*)d_in[11];
  const float* d_o2w  = (const float*)d_in[12];
  const float* c_w1   = (const float*)d_in[13];
  const float* c_b1   = (const float*)d_in[14];
  const float* c_w2   = (const float*)d_in[15];
  const float* c_b2   = (const float*)d_in[16];
  const float* c_w3   = (const float*)d_in[17];
  const float* c_b3   = (const float*)d_in[18];
  const float* fus_w  = (const float*)d_in[19];
  const float* fus_b  = (const float*)d_in[20];
  const float* tf_ng  = (const float*)d_in[21];
  const float* tf_nb  = (const float*)d_in[22];
  const float* tf_inw = (const float*)d_in[23];
  const float* tf_inb = (const float*)d_in[24];
  const float* tf_ow  = (const float*)d_in[25];
  const float* tf_ob  = (const float*)d_in[26];
  const float* tf_pw  = (const float*)d_in[27];
  const float* tf_pb  = (const float*)d_in[28];

  float* ws = (float*)d_ws;
  float* out = (float*)d_out;
  float* lnkv = ws + W_LNKV; float* lnq = ws + W_LNQ;
  float* ktbuf = ws + W_KT; float* vbuf = ws + W_V;
  float* ao = ws + W_AO;
  float* xo1 = ws + W_XO1; float* xo2 = ws + W_XO2;
  float* fused = ws + W_FUS; float* tab = ws + W_TAB;
  float* vgs1 = ws + W_VGS1; float* vgs2 = ws + W_VGS2;
  float* moutp = ws + W_MOUT; float* partp = ws + W_PART;
  float* owT1 = ws + W_OWT1; float* owT2 = ws + W_OWT2;
  float* fwT = ws + W_FWT;

  // output layout: f1(256) | f2(256) | a1(2*8*1024*256) | a2(same) — all f32
  float* a1out = out + 512;
  float* a2out = out + 512 + (size_t)kB * kG * kN * kND;

  // weight transposes
  k_trans<<<256, 256, 0, stream>>>(d_ow, owT1, 128, 512);
  k_trans<<<256, 256, 0, stream>>>(d_ow + 65536, owT2, 128, 512);
  k_trans<<<128, 256, 0, stream>>>(fus_w, fwT, 128, 256);

  k_ln<<<512, 256, 0, stream>>>(x2, lnkv, norm_g, norm_b);
  k_cpb_table<<<dim3(129, 2), 128, 0, stream>>>(c_w1, c_b1, c_w2, c_b2, c_w3, c_b3, tab);

  // ---- deform stream 1 ----
  k_ln<<<512, 256, 0, stream>>>(x1_0, lnq, norm_g, norm_b);
  k_offset<<<1024, 256, 0, stream>>>(lnq, d_qw, d_o1w, d_o1b, d_o2w, vgs1);
  k_sample_kv<<<1024, 256, 0, stream>>>(lnkv, vgs1, d_kw, d_vw, ktbuf, vbuf);
  k_attn<<<1024, 256, 0, stream>>>(lnq, d_qw, ktbuf, vbuf, vgs1, tab, a1out, ao);
  k_oproj<<<256, 256, 0, stream>>>(ao, owT1, d_ob, x1_0, xo1);

  // ---- deform stream 2 (reuses lnq/kt/v/ao; serialized on one stream) ----
  k_ln<<<512, 256, 0, stream>>>(x1_1, lnq, norm_g, norm_b);
  k_offset<<<1024, 256, 0, stream>>>(lnq, d_qw + 8192, d_o1w + 384, d_o1b + 64,
                                     d_o2w + 64, vgs2);
  k_sample_kv<<<1024, 256, 0, stream>>>(lnkv, vgs2, d_kw + 8192, d_vw + 8192,
                                        ktbuf, vbuf);
  k_attn<<<1024, 256, 0, stream>>>(lnq, d_qw + 8192, ktbuf, vbuf, vgs2,
                                   tab + (kNT + 1), a2out, ao);
  k_oproj<<<256, 256, 0, stream>>>(ao, owT2, d_ob + 128, x1_1, xo2);

  // ---- tail ----
  k_fuse<<<256, 256, 0, stream>>>(xo1, xo2, fwT, fus_b, fused);
  k_mout<<<4, 128, 0, stream>>>(x1_0, x1_1, norm_g, norm_b, tf_ng, tf_nb,
                                tf_inw, tf_inb, tf_ow, tf_ob, moutp);
  k_meanz<<<dim3(64, kB, 2), 256, 0, stream>>>(fused, norm_g, norm_b, tf_ng, tf_nb,
                                               moutp, partp);
  k_final<<<4, 256, 0, stream>>>(partp, tf_pw, tf_pb, out);

  (void)in_sizes; (void)n_in; (void)out_size; (void)ws_size;
}

// Round 5
// 177.439 us; speedup vs baseline: 3.1797x; 1.4335x over previous
//
#include <hip/hip_runtime.h>
#include <hip/hip_bf16.h>

// UniTeacherEncoder v5: LDS-staged bf16 flash-tile attention (both streams, one
// launch), d-major precomputed Q, merged stream kernels, 12 launches total.
// mha collapses (Lk=1 -> softmax==1); CPB MLP -> 16K lerp table.

namespace {

constexpr int kN  = 1024;
constexpr int kC  = 128;
constexpr int kG  = 8;
constexpr int kDH = 64;
constexpr int kND = 256;

constexpr int   kNT    = 16384;
constexpr float kRLO   = -2.0625f;   // rel in [-2.032, 2.032] guaranteed (|off|<=4)
constexpr float kRSPAN = 4.125f;

// workspace layout (float offsets)
constexpr size_t W_LNKV = 0;          // 2048 x 128 f32
constexpr size_t W_LNQ1 = 262144;     // 2048 x 128 f32
constexpr size_t W_LNQ2 = 524288;
constexpr size_t W_QT   = 786432;     // bf16 [32 bg][64 d][1024 r]  (1,048,576 f-slots)
constexpr size_t W_KT   = 1835008;    // bf16 [32 bg][64 d][256 j]   (262,144 f-slots)
constexpr size_t W_V    = 2097152;    // bf16 [32 bg][256 j][64 d]   (262,144 f-slots)
constexpr size_t W_VGS  = 2359296;    // f32 [32][256]
constexpr size_t W_AO   = 2367488;    // f32 [32 bg][1024][64]
constexpr size_t W_XO1  = 4464640;    // f32 2048x128
constexpr size_t W_XO2  = 4726784;
constexpr size_t W_FUS  = 4988928;
constexpr size_t W_TAB  = 5251072;    // f32 2 x 16385
constexpr size_t W_MOUT = 5283844;    // 4 x 128
constexpr size_t W_PART = 5284356;    // 4 x 64 x 128
constexpr size_t W_OWT1 = 5317124;    // 512 x 128
constexpr size_t W_OWT2 = 5382660;
constexpr size_t W_FWT  = 5448196;    // 256 x 128

} // namespace

__device__ __forceinline__ float wave_sum(float v) {
#pragma unroll
  for (int o = 32; o > 0; o >>= 1) v += __shfl_xor(v, o, 64);
  return v;
}
__device__ __forceinline__ float bf_lo(unsigned int u) {
  return __uint_as_float(u << 16);
}
__device__ __forceinline__ float bf_hi(unsigned int u) {
  return __uint_as_float(u & 0xffff0000u);
}
__device__ __forceinline__ unsigned int cvtpk_bf16(float lo, float hi) {
  unsigned int r;
  asm volatile("v_cvt_pk_bf16_f32 %0, %1, %2" : "=v"(r) : "v"(lo), "v"(hi));
  return r;
}

// All three weight transposes in one launch: ow1(128x512), ow2(128x512), fw(128x256).
__global__ void k_trans3(const float* __restrict__ ow, const float* __restrict__ fw,
                         float* __restrict__ owT1, float* __restrict__ owT2,
                         float* __restrict__ fwT) {
  int id = blockIdx.x * 256 + threadIdx.x;
  if (id < 65536) {
    int o = id >> 9, c = id & 511;
    owT1[c * 128 + o] = ow[id];
  } else if (id < 131072) {
    int i = id - 65536;
    int o = i >> 9, c = i & 511;
    owT2[c * 128 + o] = ow[65536 + i];
  } else if (id < 163840) {
    int i = id - 131072;
    int o = i >> 8, c = i & 255;
    fwT[c * 128 + o] = fw[i];
  }
}

// LayerNorm, one WAVE per token; three jobs in one grid (x1_0, x1_1, x2).
__global__ void k_ln3(const float* __restrict__ x1_0, const float* __restrict__ x1_1,
                      const float* __restrict__ x2, float* __restrict__ lnq1,
                      float* __restrict__ lnq2, float* __restrict__ lnkv,
                      const float* __restrict__ g, const float* __restrict__ b) {
  int w = threadIdx.x >> 6, lane = threadIdx.x & 63;
  int gr = blockIdx.x * 4 + w;
  int sel = gr >> 11, row = gr & 2047;
  const float* in = (sel == 0) ? x1_0 : (sel == 1) ? x1_1 : x2;
  float* out = (sel == 0) ? lnq1 : (sel == 1) ? lnq2 : lnkv;
  const float* xr = in + (size_t)row * kC;
  float xa = xr[lane], xb = xr[lane + 64];
  float m = wave_sum(xa + xb) * (1.f / kC);
  float da = xa - m, db = xb - m;
  float v = wave_sum(da * da + db * db) * (1.f / kC);
  float r = rsqrtf(v + 1e-5f);
  float* orow = out + (size_t)row * kC;
  orow[lane]      = da * r * g[lane] + b[lane];
  orow[lane + 64] = db * r * g[lane + 64] + b[lane + 64];
}

// Q projection into d-major bf16: qt[bg][d][r]. Block = (bg, 64-row tile).
__global__ void k_qproj(const float* __restrict__ lnq1, const float* __restrict__ lnq2,
                        const float* __restrict__ qw, __hip_bfloat16* __restrict__ qt) {
  int bg = blockIdx.x >> 4, r0 = (blockIdx.x & 15) * 64;
  int str = bg >> 4, b = (bg >> 3) & 1, g = bg & 7;
  int rl = threadIdx.x & 63, dq = threadIdx.x >> 6;  // dq in [0,4): 16 d's each
  const float* lnq = str ? lnq2 : lnq1;
  const float* xr = lnq + ((size_t)(b * kN + r0 + rl)) * kC + g * 16;
  float4 x0 = *(const float4*)(xr + 0);
  float4 x1 = *(const float4*)(xr + 4);
  float4 x2 = *(const float4*)(xr + 8);
  float4 x3 = *(const float4*)(xr + 12);
  const float* wqb = qw + (size_t)str * 8192 + (size_t)g * 1024;
#pragma unroll 4
  for (int dd = 0; dd < 16; ++dd) {
    int d = dq * 16 + dd;
    const float* wq = wqb + d * 16;
    float4 w0 = *(const float4*)(wq + 0);
    float4 w1 = *(const float4*)(wq + 4);
    float4 w2 = *(const float4*)(wq + 8);
    float4 w3 = *(const float4*)(wq + 12);
    float q = x0.x * w0.x + x0.y * w0.y + x0.z * w0.z + x0.w * w0.w
            + x1.x * w1.x + x1.y * w1.y + x1.z * w1.z + x1.w * w1.w
            + x2.x * w2.x + x2.y * w2.y + x2.z * w2.z + x2.w * w2.w
            + x3.x * w3.x + x3.y * w3.y + x3.z * w3.z + x3.w * w3.w;
    qt[((size_t)bg * 64 + d) * 1024 + r0 + rl] = __float2bfloat16(q);
  }
}

// Offsets (fused qproj + depthwise conv + gelu + dot + tanh*4 -> vgs), merged streams.
__global__ void k_offset(const float* __restrict__ lnq1, const float* __restrict__ lnq2,
                         const float* __restrict__ qw, const float* __restrict__ o1w,
                         const float* __restrict__ o1b, const float* __restrict__ o2w,
                         float* __restrict__ vgs) {
  int w = threadIdx.x >> 6, lane = threadIdx.x & 63;
  int bg = blockIdx.x >> 6, j = ((blockIdx.x & 63) << 2) + w;
  int str = bg >> 4, b = (bg >> 3) & 1, g = bg & 7;
  const float* lnq = str ? lnq2 : lnq1;
  __shared__ float xr[4][96];
  int base = j * 4 - 1;
#pragma unroll
  for (int rep = 0; rep < 2; ++rep) {
    int idx = lane + rep * 64;
    if (idx < 96) {
      int r = idx >> 4, c = idx & 15, n = base + r;
      xr[w][idx] = (n >= 0 && n < kN)
                       ? lnq[((size_t)(b * kN + n)) * kC + g * 16 + c] : 0.f;
    }
  }
  const float* wq = qw + (size_t)str * 8192 + (size_t)(g * kDH + lane) * 16;
  float acc = o1b[str * 64 + lane];
#pragma unroll
  for (int k2 = 0; k2 < 6; ++k2) {
    float qv = 0.f;
#pragma unroll
    for (int c = 0; c < 16; ++c) qv += xr[w][k2 * 16 + c] * wq[c];
    acc += qv * o1w[str * 384 + lane * 6 + k2];
  }
  float ge = 0.5f * acc * (1.f + erff(acc * 0.70710678118654752440f));
  float s = wave_sum(ge * o2w[str * 64 + lane]);
  if (lane == 0)
    vgs[bg * kND + j] = 2.f * ((float)j + tanhf(s) * 4.0f) / 255.f - 1.f;
}

// CPB MLP tabulated over rel.
__global__ void k_cpb_table(const float* __restrict__ w1, const float* __restrict__ b1,
                            const float* __restrict__ w2, const float* __restrict__ b2,
                            const float* __restrict__ w3, const float* __restrict__ b3,
                            float* __restrict__ tab) {
  int idx = blockIdx.y;
  int t = blockIdx.x * blockDim.x + threadIdx.x;
  if (t > kNT) return;
  float rel = kRLO + (kRSPAN / (float)kNT) * (float)t;
  float u = (rel >= 0.f ? 1.f : -1.f) * log1pf(fabsf(rel));
  const float* W1 = w1 + idx * 32; const float* B1 = b1 + idx * 32;
  const float* W2 = w2 + idx * 1024; const float* B2 = b2 + idx * 32;
  const float* W3 = w3 + idx * 32; const float* B3 = b3 + idx;
  float h1[32];
#pragma unroll
  for (int m = 0; m < 32; ++m) h1[m] = fmaxf(0.f, u * W1[m] + B1[m]);
  float out = B3[0];
  for (int m = 0; m < 32; ++m) {
    float a = B2[m];
#pragma unroll
    for (int k = 0; k < 32; ++k) a += h1[k] * W2[k * 32 + m];
    out += fmaxf(a, 0.f) * W3[m];
  }
  tab[(size_t)idx * (kNT + 1) + t] = out;
}

// grid_sample + k/v projections -> bf16 Kt (d-major) and V (j-major); merged streams.
__global__ void k_sample_kv(const float* __restrict__ lnkv, const float* __restrict__ vgs,
                            const float* __restrict__ kw, const float* __restrict__ vw,
                            __hip_bfloat16* __restrict__ ktout,
                            __hip_bfloat16* __restrict__ vout) {
  int w = threadIdx.x >> 6, lane = threadIdx.x & 63;
  int bg = blockIdx.x >> 6, j = ((blockIdx.x & 63) << 2) + w;
  int str = bg >> 4, b = (bg >> 3) & 1, g = bg & 7;
  __shared__ float sc[4][16];
  if (lane < 16) {
    float gr = vgs[bg * kND + j];
    float x = ((gr + 1.f) * 1024.f - 1.f) * 0.5f;
    float x0f = floorf(x);
    float w1 = x - x0f;
    int x0 = (int)x0f, x1 = x0 + 1;
    const float* src = lnkv + (size_t)b * kN * kC + g * 16 + lane;
    float v0 = (x0 >= 0 && x0 < 1024) ? src[(size_t)x0 * kC] : 0.f;
    float v1 = (x1 >= 0 && x1 < 1024) ? src[(size_t)x1 * kC] : 0.f;
    sc[w][lane] = v0 * (1.f - w1) + v1 * w1;
  }
  const float* kwr = kw + (size_t)str * 8192 + (size_t)(g * kDH + lane) * 16;
  const float* vwr = vw + (size_t)str * 8192 + (size_t)(g * kDH + lane) * 16;
  float ka = 0.f, va = 0.f;
#pragma unroll
  for (int c = 0; c < 16; ++c) { ka += sc[w][c] * kwr[c]; va += sc[w][c] * vwr[c]; }
  ktout[((size_t)bg * 64 + lane) * 256 + j] = __float2bfloat16(ka);
  vout[((size_t)bg * 256 + j) * 64 + lane] = __float2bfloat16(va);
}

// Flash-tile attention: block = (bg, 64-row tile), 256 thr, LDS-staged bf16.
// QK 8x8 reg tiles (cols split tc*4 / 128+tc*4), in-reg softmax, P bf16 in LDS,
// PV 4x4 reg tiles. Writes attn (f32, d_out) and PV result (f32, ws).
__global__ void __launch_bounds__(256, 2)
k_attn(const __hip_bfloat16* __restrict__ qt_g, const __hip_bfloat16* __restrict__ kt_g,
       const __hip_bfloat16* __restrict__ v_g, const float* __restrict__ vgs,
       const float* __restrict__ tab, float* __restrict__ aout,
       float* __restrict__ attout) {
  int bg = blockIdx.x >> 4, tile = blockIdx.x & 15;
  int i0 = tile * 64;
  int str = bg >> 4;
  int t = threadIdx.x;
  int w = t >> 6, lane = t & 63;
  int tr = t >> 5, tc = t & 31;

  __shared__ __hip_bfloat16 qt[64 * 64];   // [k][r]
  __shared__ __hip_bfloat16 stg[4096];     // Kt chunk [16][256] / V chunk [64][64]
  __shared__ __hip_bfloat16 P[64 * 260];   // pad 260 -> conflict-free PV reads

  const float* tabs = tab + str * (kNT + 1);

  // ---- stage qt tile (8 KB): 2 float4 per lane ----
#pragma unroll
  for (int it = 0; it < 2; ++it) {
    int e = (w * 2 + it) * 512 + lane * 8;     // bf16 elem index
    int d = e >> 6, r = e & 63;
    *(float4*)&qt[e] = *(const float4*)(qt_g + ((size_t)bg * 64 + d) * 1024 + i0 + r);
  }

  float4 accA[8], accB[8];
#pragma unroll
  for (int rr = 0; rr < 8; ++rr) { accA[rr] = {0,0,0,0}; accB[rr] = {0,0,0,0}; }

  // ---- QK over 4 d-chunks ----
  for (int ch = 0; ch < 4; ++ch) {
    __syncthreads();  // prev chunk consumed (no-op first iter)
#pragma unroll
    for (int it = 0; it < 2; ++it) {
      int e = (w * 2 + it) * 512 + lane * 8;
      int d = e >> 8, j = e & 255;
      *(float4*)&stg[e] =
          *(const float4*)(kt_g + ((size_t)bg * 64 + ch * 16 + d) * 256 + j);
    }
    __syncthreads();
#pragma unroll
    for (int k = 0; k < 16; ++k) {
      uint4 aq = *(const uint4*)&qt[(ch * 16 + k) * 64 + tr * 8];
      float ar[8] = {bf_lo(aq.x), bf_hi(aq.x), bf_lo(aq.y), bf_hi(aq.y),
                     bf_lo(aq.z), bf_hi(aq.z), bf_lo(aq.w), bf_hi(aq.w)};
      uint2 b0 = *(const uint2*)&stg[k * 256 + tc * 4];
      uint2 b1 = *(const uint2*)&stg[k * 256 + 128 + tc * 4];
      float4 bA = {bf_lo(b0.x), bf_hi(b0.x), bf_lo(b0.y), bf_hi(b0.y)};
      float4 bB = {bf_lo(b1.x), bf_hi(b1.x), bf_lo(b1.y), bf_hi(b1.y)};
#pragma unroll
      for (int rr = 0; rr < 8; ++rr) {
        accA[rr].x += ar[rr] * bA.x; accA[rr].y += ar[rr] * bA.y;
        accA[rr].z += ar[rr] * bA.z; accA[rr].w += ar[rr] * bA.w;
        accB[rr].x += ar[rr] * bB.x; accB[rr].y += ar[rr] * bB.y;
        accB[rr].z += ar[rr] * bB.z; accB[rr].w += ar[rr] * bB.w;
      }
    }
  }

  // ---- bias + softmax (rows spread over tc lanes; shfl_xor over tc bits) ----
  float4 vgA = *(const float4*)&vgs[bg * 256 + tc * 4];
  float4 vgB = *(const float4*)&vgs[bg * 256 + 128 + tc * 4];
  float* aoutb = aout + (size_t)str * 4194304 + ((size_t)(bg & 15) * 1024) * 256;
#pragma unroll
  for (int rr = 0; rr < 8; ++rr) {
    int i = i0 + tr * 8 + rr;
    float seq = 2.f * (float)i / 1023.f - 1.f;
    float s[8];
    {
      const float* va = (const float*)&vgA;
      const float* vb = (const float*)&vgB;
      float* pa = (float*)&accA[rr];
      float* pb = (float*)&accB[rr];
#pragma unroll
      for (int c = 0; c < 4; ++c) {
        float rel = seq - va[c];
        float ft = (rel - kRLO) * ((float)kNT / kRSPAN);
        ft = fminf(fmaxf(ft, 0.f), 16383.999f);
        int ix = (int)ft; float fw = ft - (float)ix;
        s[c] = pa[c] * 0.125f + tabs[ix] * (1.f - fw) + tabs[ix + 1] * fw;
        rel = seq - vb[c];
        ft = (rel - kRLO) * ((float)kNT / kRSPAN);
        ft = fminf(fmaxf(ft, 0.f), 16383.999f);
        ix = (int)ft; fw = ft - (float)ix;
        s[4 + c] = pb[c] * 0.125f + tabs[ix] * (1.f - fw) + tabs[ix + 1] * fw;
      }
    }
    float m = fmaxf(fmaxf(fmaxf(s[0], s[1]), fmaxf(s[2], s[3])),
                    fmaxf(fmaxf(s[4], s[5]), fmaxf(s[6], s[7])));
#pragma unroll
    for (int mk = 1; mk <= 16; mk <<= 1) m = fmaxf(m, __shfl_xor(m, mk, 64));
    float e[8], sum = 0.f;
#pragma unroll
    for (int c = 0; c < 8; ++c) { e[c] = expf(s[c] - m); sum += e[c]; }
#pragma unroll
    for (int mk = 1; mk <= 16; mk <<= 1) sum += __shfl_xor(sum, mk, 64);
    float inv = 1.f / sum;
#pragma unroll
    for (int c = 0; c < 8; ++c) e[c] *= inv;
    float* arow = aoutb + (size_t)i * 256;
    *(float4*)&arow[tc * 4]       = {e[0], e[1], e[2], e[3]};
    *(float4*)&arow[128 + tc * 4] = {e[4], e[5], e[6], e[7]};
    uint2 pl = {cvtpk_bf16(e[0], e[1]), cvtpk_bf16(e[2], e[3])};
    uint2 ph = {cvtpk_bf16(e[4], e[5]), cvtpk_bf16(e[6], e[7])};
    *(uint2*)&P[(tr * 8 + rr) * 260 + tc * 4]       = pl;
    *(uint2*)&P[(tr * 8 + rr) * 260 + 128 + tc * 4] = ph;
  }

  // ---- PV over 4 j-chunks: thread (rg,dg) -> rows rg*4..+3, d dg*4..+3 ----
  int rg = t >> 4, dg = t & 15;
  float4 acc[4] = {{0,0,0,0},{0,0,0,0},{0,0,0,0},{0,0,0,0}};
  for (int ch = 0; ch < 4; ++ch) {
    __syncthreads();  // prev stg reads + (ch0) P writes complete
#pragma unroll
    for (int it = 0; it < 2; ++it) {
      int e = (w * 2 + it) * 512 + lane * 8;
      int j = e >> 6, d = e & 63;
      *(float4*)&stg[e] =
          *(const float4*)(v_g + ((size_t)bg * 256 + ch * 64 + j) * 64 + d);
    }
    __syncthreads();
#pragma unroll 4
    for (int jq = 0; jq < 16; ++jq) {
      int jl = jq * 4;
      int jg = ch * 64 + jl;
      uint2 p0 = *(const uint2*)&P[(rg * 4 + 0) * 260 + jg];
      uint2 p1 = *(const uint2*)&P[(rg * 4 + 1) * 260 + jg];
      uint2 p2 = *(const uint2*)&P[(rg * 4 + 2) * 260 + jg];
      uint2 p3 = *(const uint2*)&P[(rg * 4 + 3) * 260 + jg];
      float a0[4] = {bf_lo(p0.x), bf_hi(p0.x), bf_lo(p0.y), bf_hi(p0.y)};
      float a1[4] = {bf_lo(p1.x), bf_hi(p1.x), bf_lo(p1.y), bf_hi(p1.y)};
      float a2[4] = {bf_lo(p2.x), bf_hi(p2.x), bf_lo(p2.y), bf_hi(p2.y)};
      float a3[4] = {bf_lo(p3.x), bf_hi(p3.x), bf_lo(p3.y), bf_hi(p3.y)};
#pragma unroll
      for (int jj = 0; jj < 4; ++jj) {
        uint2 vv = *(const uint2*)&stg[(jl + jj) * 64 + dg * 4];
        float4 v4 = {bf_lo(vv.x), bf_hi(vv.x), bf_lo(vv.y), bf_hi(vv.y)};
        acc[0].x += a0[jj] * v4.x; acc[0].y += a0[jj] * v4.y;
        acc[0].z += a0[jj] * v4.z; acc[0].w += a0[jj] * v4.w;
        acc[1].x += a1[jj] * v4.x; acc[1].y += a1[jj] * v4.y;
        acc[1].z += a1[jj] * v4.z; acc[1].w += a1[jj] * v4.w;
        acc[2].x += a2[jj] * v4.x; acc[2].y += a2[jj] * v4.y;
        acc[2].z += a2[jj] * v4.z; acc[2].w += a2[jj] * v4.w;
        acc[3].x += a3[jj] * v4.x; acc[3].y += a3[jj] * v4.y;
        acc[3].z += a3[jj] * v4.z; acc[3].w += a3[jj] * v4.w;
      }
    }
  }
#pragma unroll
  for (int rr = 0; rr < 4; ++rr)
    *(float4*)&attout[((size_t)bg * 1024 + i0 + rg * 4 + rr) * 64 + dg * 4] = acc[rr];
}

// out-projection + residual, merged streams. Block = 8 tokens, 256 thr.
__global__ void k_oproj(const float* __restrict__ ao, const float* __restrict__ owT1,
                        const float* __restrict__ owT2, const float* __restrict__ ob,
                        const float* __restrict__ x1_0, const float* __restrict__ x1_1,
                        float* __restrict__ xo1, float* __restrict__ xo2) {
  int tok0 = blockIdx.x * 8;
  int str = tok0 >> 11;
  const float* owT = str ? owT2 : owT1;
  const float* x1 = str ? x1_1 : x1_0;
  float* xout = str ? xo2 : xo1;
  int t = threadIdx.x;
  int o = t & 127, th = t >> 7;
  __shared__ float s[8 * 512];
#pragma unroll
  for (int k = 0; k < 16; ++k) {
    int fi = t + k * 256;
    int tok = fi >> 9, c = fi & 511;
    int tg = tok0 + tok;
    int b = (tg >> 10) & 1, n = tg & 1023;
    s[fi] = ao[((size_t)(str * 16 + b * 8 + (c >> 6)) * 1024 + n) * 64 + (c & 63)];
  }
  __syncthreads();
  float acc0 = 0.f, acc1 = 0.f, acc2 = 0.f, acc3 = 0.f;
  for (int c = 0; c < 512; c += 4) {
    float wa = owT[(c + 0) * kC + o];
    float wb = owT[(c + 1) * kC + o];
    float wc = owT[(c + 2) * kC + o];
    float wd = owT[(c + 3) * kC + o];
    const float4 sa = *(const float4*)&s[(th + 0) * 512 + c];
    const float4 sb = *(const float4*)&s[(th + 2) * 512 + c];
    const float4 sc4 = *(const float4*)&s[(th + 4) * 512 + c];
    const float4 sd = *(const float4*)&s[(th + 6) * 512 + c];
    acc0 += sa.x * wa + sa.y * wb + sa.z * wc + sa.w * wd;
    acc1 += sb.x * wa + sb.y * wb + sb.z * wc + sb.w * wd;
    acc2 += sc4.x * wa + sc4.y * wb + sc4.z * wc + sc4.w * wd;
    acc3 += sd.x * wa + sd.y * wb + sd.z * wc + sd.w * wd;
  }
  float bias = ob[str * 128 + o];
  float accs[4] = {acc0, acc1, acc2, acc3};
#pragma unroll
  for (int k = 0; k < 4; ++k) {
    int tg = (tok0 & 2047) + th + k * 2;   // token within stream (b*1024+n)
    size_t oo = (size_t)tg * kC + o;
    xout[oo] = x1[oo] + accs[k] + bias;
  }
}

// fusion: concat(xo1,xo2) @ fwT + fb.
__global__ void k_fuse(const float* __restrict__ xo1, const float* __restrict__ xo2,
                       const float* __restrict__ fwT, const float* __restrict__ fb,
                       float* __restrict__ fused) {
  int tok0 = blockIdx.x * 8;
  int t = threadIdx.x;
  int o = t & 127, th = t >> 7;
  __shared__ float s[8 * 256];
#pragma unroll
  for (int k = 0; k < 8; ++k) {
    int fi = t + k * 256;
    int tok = fi >> 8, c = fi & 255;
    const float* src = (c < 128) ? xo1 : xo2;
    s[fi] = src[(size_t)(tok0 + tok) * kC + (c & 127)];
  }
  __syncthreads();
  float acc0 = 0.f, acc1 = 0.f, acc2 = 0.f, acc3 = 0.f;
  for (int c = 0; c < 256; c += 4) {
    float wa = fwT[(c + 0) * kC + o];
    float wb = fwT[(c + 1) * kC + o];
    float wc = fwT[(c + 2) * kC + o];
    float wd = fwT[(c + 3) * kC + o];
    const float4 sa = *(const float4*)&s[(th + 0) * 256 + c];
    const float4 sb = *(const float4*)&s[(th + 2) * 256 + c];
    const float4 sc4 = *(const float4*)&s[(th + 4) * 256 + c];
    const float4 sd = *(const float4*)&s[(th + 6) * 256 + c];
    acc0 += sa.x * wa + sa.y * wb + sa.z * wc + sa.w * wd;
    acc1 += sb.x * wa + sb.y * wb + sb.z * wc + sb.w * wd;
    acc2 += sc4.x * wa + sc4.y * wb + sc4.z * wc + sc4.w * wd;
    acc3 += sd.x * wa + sd.y * wb + sd.z * wc + sd.w * wd;
  }
  float bias = fb[o];
  float accs[4] = {acc0, acc1, acc2, acc3};
#pragma unroll
  for (int k = 0; k < 4; ++k)
    fused[(size_t)(tok0 + th + k * 2) * kC + o] = accs[k] + bias;
}

// mha v-path: mout = (ln_tf(ln(x1_i[b,0])) @ Wv.T + bv) @ Wo.T + bo
__global__ void k_mout(const float* __restrict__ x1_0, const float* __restrict__ x1_1,
                       const float* __restrict__ ng, const float* __restrict__ nb,
                       const float* __restrict__ tfng, const float* __restrict__ tfnb,
                       const float* __restrict__ inw, const float* __restrict__ inb,
                       const float* __restrict__ ow, const float* __restrict__ ob,
                       float* __restrict__ mout) {
  int i = blockIdx.x >> 1, b = blockIdx.x & 1, t = threadIdx.x;
  __shared__ float red[2];
  __shared__ float s1[128];
  __shared__ float s2[128];
  const float* xs = (i ? x1_1 : x1_0) + (size_t)b * kN * kC;
  float x = xs[t];
  float s = wave_sum(x);
  if ((t & 63) == 0) red[t >> 6] = s;
  __syncthreads();
  float m1 = (red[0] + red[1]) * (1.f / kC);
  __syncthreads();
  float d1 = x - m1;
  float ss = wave_sum(d1 * d1);
  if ((t & 63) == 0) red[t >> 6] = ss;
  __syncthreads();
  float v1 = (red[0] + red[1]) * (1.f / kC);
  __syncthreads();
  float t0 = d1 * rsqrtf(v1 + 1e-5f) * ng[t] + nb[t];
  s = wave_sum(t0);
  if ((t & 63) == 0) red[t >> 6] = s;
  __syncthreads();
  float m2 = (red[0] + red[1]) * (1.f / kC);
  __syncthreads();
  float d2 = t0 - m2;
  ss = wave_sum(d2 * d2);
  if ((t & 63) == 0) red[t >> 6] = ss;
  __syncthreads();
  float v2 = (red[0] + red[1]) * (1.f / kC);
  float t1 = d2 * rsqrtf(v2 + 1e-5f) * tfng[i * kC + t] + tfnb[i * kC + t];
  s1[t] = t1;
  __syncthreads();
  {
    float a0 = 0.f;
    const float* wr = inw + (size_t)i * 384 * kC + (size_t)(256 + t) * kC;
    for (int c = 0; c < 128; ++c) a0 += s1[c] * wr[c];
    s2[t] = inb[i * 384 + 256 + t] + a0;
  }
  __syncthreads();
  {
    float a0 = 0.f;
    const float* wr2 = ow + (size_t)i * kC * kC + (size_t)t * kC;
    for (int c = 0; c < 128; ++c) a0 += s2[c] * wr2[c];
    mout[blockIdx.x * kC + t] = ob[i * kC + t] + a0;
  }
}

// Double-LN + mout add; wave per token; per-chunk partial sums.
__global__ void k_meanz(const float* __restrict__ fused, const float* __restrict__ ng,
                        const float* __restrict__ nb, const float* __restrict__ tfng,
                        const float* __restrict__ tfnb, const float* __restrict__ mout,
                        float* __restrict__ partial) {
  int chunk = blockIdx.x, b = blockIdx.y, i = blockIdx.z;
  int w = threadIdx.x >> 6, lane = threadIdx.x & 63;
  int c = lane, c2 = lane + 64;
  float moa = mout[(i * 2 + b) * kC + c], mob = mout[(i * 2 + b) * kC + c2];
  float g1a = ng[c], b1a = nb[c], g1b = ng[c2], b1b = nb[c2];
  float g2a = tfng[i * kC + c], b2a = tfnb[i * kC + c];
  float g2b = tfng[i * kC + c2], b2b = tfnb[i * kC + c2];
  float acca = 0.f, accb = 0.f;
#pragma unroll
  for (int it = 0; it < 4; ++it) {
    int tok = chunk * 16 + it * 4 + w;
    const float* xr = fused + ((size_t)(b * kN + tok)) * kC;
    float xa = xr[c], xb = xr[c2];
    float m1 = wave_sum(xa + xb) * (1.f / kC);
    float da = xa - m1, db = xb - m1;
    float v1 = wave_sum(da * da + db * db) * (1.f / kC);
    float r1 = rsqrtf(v1 + 1e-5f);
    float za = da * r1 * g1a + b1a + moa;
    float zb = db * r1 * g1b + b1b + mob;
    float m2 = wave_sum(za + zb) * (1.f / kC);
    float ea = za - m2, eb = zb - m2;
    float v2 = wave_sum(ea * ea + eb * eb) * (1.f / kC);
    float r2 = rsqrtf(v2 + 1e-5f);
    acca += ea * r2 * g2a + b2a;
    accb += eb * r2 * g2b + b2b;
  }
  __shared__ float red[4][128];
  red[w][c] = acca; red[w][c2] = accb;
  __syncthreads();
  if (w == 0) {
    float pa = red[0][c] + red[1][c] + red[2][c] + red[3][c];
    float pb = red[0][c2] + red[1][c2] + red[2][c2] + red[3][c2];
    float* pr = partial + ((size_t)(i * 2 + b) * 64 + chunk) * kC;
    pr[c] = pa; pr[c2] = pb;
  }
}

__global__ void k_final(const float* __restrict__ partial, const float* __restrict__ pw,
                        const float* __restrict__ pb, float* __restrict__ out) {
  int ib = blockIdx.x;
  int i = ib >> 1, t = threadIdx.x;
  int c = t & 127, half = t >> 7;
  float a = 0.f;
  for (int ch = half * 32; ch < half * 32 + 32; ++ch)
    a += partial[((size_t)ib * 64 + ch) * kC + c];
  __shared__ float s[256];
  s[half * 128 + c] = a;
  __syncthreads();
  if (t < 128) s[t] = (s[t] + s[128 + t]) * (1.f / (float)kN);
  __syncthreads();
  if (t < 128) {
    float a0 = 0.f;
    const float* wr = pw + (size_t)i * kC * kC + (size_t)t * kC;
    for (int cc = 0; cc < 128; ++cc) a0 += s[cc] * wr[cc];
    out[ib * 128 + t] = tanhf(pb[i * kC + t] + a0);
  }
}

extern "C" void kernel_launch(void* const* d_in, const int* in_sizes, int n_in,
                              void* d_out, int out_size, void* d_ws, size_t ws_size,
                              hipStream_t stream) {
  const float* x1_0   = (const float*)d_in[0];
  const float* x1_1   = (const float*)d_in[1];
  const float* x2     = (const float*)d_in[2];
  const float* norm_g = (const float*)d_in[3];
  const float* norm_b = (const float*)d_in[4];
  const float* d_qw   = (const float*)d_in[5];
  const float* d_kw   = (const float*)d_in[6];
  const float* d_vw   = (const float*)d_in[7];
  const float* d_ow   = (const float*)d_in[8];
  const float* d_ob   = (const float*)d_in[9];
  const float* d_o1w  = (const float*)d_in[10];
  const float* d_o1b  = (const float*)d_in[11];
  const float* d_o2w  = (const float*)d_in[12];
  const float* c_w1   = (const float*)d_in[13];
  const float* c_b1   = (const float*)d_in[14];
  const float* c_w2   = (const float*)d_in[15];
  const float* c_b2   = (const float*)d_in[16];
  const float* c_w3   = (const float*)d_in[17];
  const float* c_b3   = (const float*)d_in[18];
  const float* fus_w  = (const float*)d_in[19];
  const float* fus_b  = (const float*)d_in[20];
  const float* tf_ng  = (const float*)d_in[21];
  const float* tf_nb  = (const float*)d_in[22];
  const float* tf_inw = (const float*)d_in[23];
  const float* tf_inb = (const float*)d_in[24];
  const float* tf_ow  = (const float*)d_in[25];
  const float* tf_ob  = (const float*)d_in[26];
  const float* tf_pw  = (const float*)d_in[27];
  const float* tf_pb  = (const float*)d_in[28];

  float* ws = (float*)d_ws;
  float* out = (float*)d_out;
  float* lnkv = ws + W_LNKV;
  float* lnq1 = ws + W_LNQ1; float* lnq2 = ws + W_LNQ2;
  __hip_bfloat16* qtb = (__hip_bfloat16*)(ws + W_QT);
  __hip_bfloat16* ktb = (__hip_bfloat16*)(ws + W_KT);
  __hip_bfloat16* vb  = (__hip_bfloat16*)(ws + W_V);
  float* vgsw = ws + W_VGS;
  float* ao = ws + W_AO;
  float* xo1 = ws + W_XO1; float* xo2 = ws + W_XO2;
  float* fused = ws + W_FUS; float* tab = ws + W_TAB;
  float* moutp = ws + W_MOUT; float* partp = ws + W_PART;
  float* owT1 = ws + W_OWT1; float* owT2 = ws + W_OWT2;
  float* fwT = ws + W_FWT;

  // output: f1(256) | f2(256) | a1(2*8*1024*256) | a2(same), all f32
  float* aoutb = out + 512;

  k_trans3<<<640, 256, 0, stream>>>(d_ow, fus_w, owT1, owT2, fwT);
  k_ln3<<<1536, 256, 0, stream>>>(x1_0, x1_1, x2, lnq1, lnq2, lnkv, norm_g, norm_b);
  k_cpb_table<<<dim3(129, 2), 128, 0, stream>>>(c_w1, c_b1, c_w2, c_b2, c_w3, c_b3, tab);

  k_qproj<<<512, 256, 0, stream>>>(lnq1, lnq2, d_qw, qtb);
  k_offset<<<2048, 256, 0, stream>>>(lnq1, lnq2, d_qw, d_o1w, d_o1b, d_o2w, vgsw);
  k_sample_kv<<<2048, 256, 0, stream>>>(lnkv, vgsw, d_kw, d_vw, ktb, vb);
  k_attn<<<512, 256, 0, stream>>>(qtb, ktb, vb, vgsw, tab, aoutb, ao);
  k_oproj<<<512, 256, 0, stream>>>(ao, owT1, owT2, d_ob, x1_0, x1_1, xo1, xo2);

  k_fuse<<<256, 256, 0, stream>>>(xo1, xo2, fwT, fus_b, fused);
  k_mout<<<4, 128, 0, stream>>>(x1_0, x1_1, norm_g, norm_b, tf_ng, tf_nb,
                                tf_inw, tf_inb, tf_ow, tf_ob, moutp);
  k_meanz<<<dim3(64, 2, 2), 256, 0, stream>>>(fused, norm_g, norm_b, tf_ng, tf_nb,
                                              moutp, partp);
  k_final<<<4, 256, 0, stream>>>(partp, tf_pw, tf_pb, out);

  (void)in_sizes; (void)n_in; (void)out_size; (void)ws_size;
}